// Round 1
// baseline (602.537 us; speedup 1.0000x reference)
//
#include <hip/hip_runtime.h>

typedef short v8s __attribute__((ext_vector_type(8)));
typedef float v4f __attribute__((ext_vector_type(4)));

#define T_TOK 2048
#define DD 2048
#define FF 4096
#define EE 8
#define BM 128
#define BN 128
#define BK 64
#define MT_MAX 40
#define MAXROWS 5120

// workspace layout (bytes)
#define WS_COUNTS 0
#define WS_FILL   32
#define WS_ROWOFF 64
#define WS_TOPE   128
#define WS_TOPW   (WS_TOPE + T_TOK * 2 * 4)   // 16512
#define WS_IDS    (WS_TOPW + T_TOK * 2 * 4)   // 32896
#define WS_WTS    (WS_IDS + MAXROWS * 4)      // 53376
#define WS_ZERO   (WS_WTS + MAXROWS * 4)      // 73856 bytes zeroed each launch
#define WS_H      73984ul                     // 256-aligned; bf16 H[5120][4096]

// XOR-swizzled byte offset within a [rows][64 bf16] LDS tile (row stride 128B)
#define SWZ(r, kb) ((((r) * 128) + (kb)) ^ (((r) & 7) << 4))

static __device__ __forceinline__ short f2bf(float f) {
  return __builtin_bit_cast(short, static_cast<__bf16>(f));
}

// ---------------- router: fp32 logits, softmax, top-2 ----------------
__global__ __launch_bounds__(256) void router_k(
    const float* __restrict__ x, const float* __restrict__ gw,
    int* __restrict__ counts, int* __restrict__ tope, float* __restrict__ topw) {
  const int lane = threadIdx.x & 63;
  const int t = blockIdx.x * 4 + (threadIdx.x >> 6);
  if (t >= T_TOK) return;
  float acc[EE] = {0.f, 0.f, 0.f, 0.f, 0.f, 0.f, 0.f, 0.f};
  const float* xr = x + (size_t)t * DD;
  for (int i = 0; i < DD / 64; ++i) {
    int k = i * 64 + lane;
    float xv = xr[k];
    const v4f* g = (const v4f*)(gw + (size_t)k * EE);
    v4f g0 = g[0], g1 = g[1];
    acc[0] += xv * g0[0]; acc[1] += xv * g0[1]; acc[2] += xv * g0[2]; acc[3] += xv * g0[3];
    acc[4] += xv * g1[0]; acc[5] += xv * g1[1]; acc[6] += xv * g1[2]; acc[7] += xv * g1[3];
  }
  #pragma unroll
  for (int e = 0; e < EE; ++e) {
    #pragma unroll
    for (int off = 32; off > 0; off >>= 1) acc[e] += __shfl_xor(acc[e], off);
  }
  if (lane == 0) {
    float m = acc[0];
    #pragma unroll
    for (int e = 1; e < EE; ++e) m = fmaxf(m, acc[e]);
    float p[EE], s = 0.f;
    #pragma unroll
    for (int e = 0; e < EE; ++e) { p[e] = expf(acc[e] - m); s += p[e]; }
    float inv = 1.f / s;
    #pragma unroll
    for (int e = 0; e < EE; ++e) p[e] *= inv;
    int e1 = 0;
    #pragma unroll
    for (int e = 1; e < EE; ++e) if (p[e] > p[e1]) e1 = e;
    int e2 = (e1 == 0) ? 1 : 0;
    #pragma unroll
    for (int e = 0; e < EE; ++e) if (e != e1 && p[e] > p[e2]) e2 = e;
    tope[2 * t] = e1;  tope[2 * t + 1] = e2;
    topw[2 * t] = p[e1]; topw[2 * t + 1] = p[e2];
    atomicAdd(&counts[e1], 1);
    atomicAdd(&counts[e2], 1);
  }
}

// ---------------- per-expert padded row offsets ----------------
__global__ void offsets_k(const int* __restrict__ counts, int* __restrict__ rowoff) {
  if (threadIdx.x == 0) {
    int off = 0;
    #pragma unroll
    for (int e = 0; e < EE; ++e) {
      rowoff[e] = off;
      off += ((counts[e] + BM - 1) / BM) * BM;
    }
  }
}

// ---------------- scatter token ids/weights into expert-sorted slots ----------------
__global__ __launch_bounds__(256) void scatter_k(
    const int* __restrict__ tope, const float* __restrict__ topw,
    const int* __restrict__ rowoff, int* __restrict__ fill,
    int* __restrict__ ids, float* __restrict__ wts) {
  const int t = blockIdx.x * 256 + threadIdx.x;
  if (t >= T_TOK) return;
  #pragma unroll
  for (int j = 0; j < 2; ++j) {
    int e = tope[2 * t + j];
    int pos = rowoff[e] + atomicAdd(&fill[e], 1);
    ids[pos] = t;
    wts[pos] = topw[2 * t + j];
  }
}

// ---------------- GEMM1: H = silu(X@W1) * (X@W3), bf16 out ----------------
__global__ __launch_bounds__(256, 2) void gemm1_k(
    const float* __restrict__ x, const float* __restrict__ w1,
    const float* __restrict__ w3, const int* __restrict__ counts,
    const int* __restrict__ rowoff, const int* __restrict__ ids,
    unsigned short* __restrict__ H) {
  const int nt = blockIdx.x, mt = blockIdx.y;
  int expert = -1;
  #pragma unroll
  for (int e = 0; e < EE; ++e) {
    int rs = rowoff[e];
    int tl = (counts[e] + BM - 1) / BM;
    if (mt * BM >= rs && mt * BM < rs + tl * BM) expert = e;
  }
  if (expert < 0) return;
  const int m0 = mt * BM, n0 = nt * BN;

  __shared__ unsigned short sA[BM * BK];
  __shared__ unsigned short sB0[BN * BK];
  __shared__ unsigned short sB1[BN * BK];

  const int tid = threadIdx.x;
  const int lane = tid & 63;
  const int wid = tid >> 6;
  const int wm = (wid >> 1) * 64, wn = (wid & 1) * 64;
  const int lr = lane & 15, lg = lane >> 4;

  // A staging: thread covers rows a_row0+32g, k-chunk a_kc..a_kc+8
  const int a_row0 = tid >> 3;
  const int a_kc = (tid & 7) * 8;
  const float* aptr[4];
  #pragma unroll
  for (int g = 0; g < 4; ++g)
    aptr[g] = x + (size_t)ids[m0 + a_row0 + g * 32] * DD + a_kc;

  // B staging: thread covers 4 f-rows (b_f4..+4) x 8 k (b_k8..+8), transposed into LDS
  const int b_f4 = (tid & 31) * 4;
  const int b_k8 = (tid >> 5) * 8;
  const float* wb1 = w1 + (size_t)expert * DD * FF + n0 + b_f4 + (size_t)b_k8 * FF;
  const float* wb3 = w3 + (size_t)expert * DD * FF + n0 + b_f4 + (size_t)b_k8 * FF;

  v4f acc1[4][4], acc3[4][4];
  #pragma unroll
  for (int i = 0; i < 4; ++i)
    #pragma unroll
    for (int j = 0; j < 4; ++j) {
      acc1[i][j] = (v4f){0.f, 0.f, 0.f, 0.f};
      acc3[i][j] = (v4f){0.f, 0.f, 0.f, 0.f};
    }

  for (int kt = 0; kt < DD / BK; ++kt) {
    #pragma unroll
    for (int g = 0; g < 4; ++g) {
      const float* p = aptr[g] + (size_t)kt * BK;
      v4f u0 = *(const v4f*)p;
      v4f u1 = *(const v4f*)(p + 4);
      v8s h;
      h[0] = f2bf(u0[0]); h[1] = f2bf(u0[1]); h[2] = f2bf(u0[2]); h[3] = f2bf(u0[3]);
      h[4] = f2bf(u1[0]); h[5] = f2bf(u1[1]); h[6] = f2bf(u1[2]); h[7] = f2bf(u1[3]);
      *(v8s*)((char*)sA + SWZ(a_row0 + g * 32, a_kc * 2)) = h;
    }
    {
      const float* p = wb1 + (size_t)kt * BK * FF;
      v4f r[8];
      #pragma unroll
      for (int j = 0; j < 8; ++j) r[j] = *(const v4f*)(p + (size_t)j * FF);
      #pragma unroll
      for (int c = 0; c < 4; ++c) {
        v8s h;
        #pragma unroll
        for (int j = 0; j < 8; ++j) h[j] = f2bf(r[j][c]);
        *(v8s*)((char*)sB0 + SWZ(b_f4 + c, b_k8 * 2)) = h;
      }
      p = wb3 + (size_t)kt * BK * FF;
      #pragma unroll
      for (int j = 0; j < 8; ++j) r[j] = *(const v4f*)(p + (size_t)j * FF);
      #pragma unroll
      for (int c = 0; c < 4; ++c) {
        v8s h;
        #pragma unroll
        for (int j = 0; j < 8; ++j) h[j] = f2bf(r[j][c]);
        *(v8s*)((char*)sB1 + SWZ(b_f4 + c, b_k8 * 2)) = h;
      }
    }
    __syncthreads();
    #pragma unroll
    for (int ks = 0; ks < 2; ++ks) {
      const int kb = ks * 64 + lg * 16;
      v8s a[4], b1[4], b3[4];
      #pragma unroll
      for (int m = 0; m < 4; ++m)
        a[m] = *(const v8s*)((const char*)sA + SWZ(wm + m * 16 + lr, kb));
      #pragma unroll
      for (int n = 0; n < 4; ++n) {
        b1[n] = *(const v8s*)((const char*)sB0 + SWZ(wn + n * 16 + lr, kb));
        b3[n] = *(const v8s*)((const char*)sB1 + SWZ(wn + n * 16 + lr, kb));
      }
      #pragma unroll
      for (int m = 0; m < 4; ++m)
        #pragma unroll
        for (int n = 0; n < 4; ++n) {
          acc1[m][n] = __builtin_amdgcn_mfma_f32_16x16x32_bf16(a[m], b1[n], acc1[m][n], 0, 0, 0);
          acc3[m][n] = __builtin_amdgcn_mfma_f32_16x16x32_bf16(a[m], b3[n], acc3[m][n], 0, 0, 0);
        }
    }
    __syncthreads();
  }
  #pragma unroll
  for (int m = 0; m < 4; ++m)
    #pragma unroll
    for (int n = 0; n < 4; ++n)
      #pragma unroll
      for (int r = 0; r < 4; ++r) {
        int row = wm + m * 16 + lg * 4 + r;
        int col = wn + n * 16 + lr;
        float g = acc1[m][n][r];
        float u = acc3[m][n][r];
        float hv = (g / (1.f + expf(-g))) * u;
        H[(size_t)(m0 + row) * FF + (n0 + col)] = (unsigned short)f2bf(hv);
      }
}

// ---------------- GEMM2: out[tok] += w * (H @ W2) ----------------
__global__ __launch_bounds__(256, 2) void gemm2_k(
    const unsigned short* __restrict__ H, const float* __restrict__ w2,
    const int* __restrict__ counts, const int* __restrict__ rowoff,
    const int* __restrict__ ids, const float* __restrict__ wts,
    float* __restrict__ out) {
  const int nt = blockIdx.x, mt = blockIdx.y;
  int expert = -1;
  #pragma unroll
  for (int e = 0; e < EE; ++e) {
    int rs = rowoff[e];
    int tl = (counts[e] + BM - 1) / BM;
    if (mt * BM >= rs && mt * BM < rs + tl * BM) expert = e;
  }
  if (expert < 0) return;
  const int m0 = mt * BM, n0 = nt * BN;

  __shared__ unsigned short sA[BM * BK];
  __shared__ unsigned short sB[BN * BK];

  const int tid = threadIdx.x;
  const int lane = tid & 63;
  const int wid = tid >> 6;
  const int wm = (wid >> 1) * 64, wn = (wid & 1) * 64;
  const int lr = lane & 15, lg = lane >> 4;

  const int a_row0 = tid >> 3;
  const int a_kc = (tid & 7) * 8;
  const unsigned short* ha = H + (size_t)(m0 + a_row0) * FF + a_kc;
  const int b_f4 = (tid & 31) * 4;   // output cols (d)
  const int b_k8 = (tid >> 5) * 8;   // k rows (f)
  const float* wb = w2 + (size_t)expert * FF * DD + n0 + b_f4 + (size_t)b_k8 * DD;

  v4f acc[4][4];
  #pragma unroll
  for (int i = 0; i < 4; ++i)
    #pragma unroll
    for (int j = 0; j < 4; ++j) acc[i][j] = (v4f){0.f, 0.f, 0.f, 0.f};

  for (int kt = 0; kt < FF / BK; ++kt) {
    #pragma unroll
    for (int g = 0; g < 4; ++g) {
      v8s h = *(const v8s*)(ha + (size_t)g * 32 * FF + kt * BK);
      *(v8s*)((char*)sA + SWZ(a_row0 + g * 32, a_kc * 2)) = h;
    }
    {
      const float* p = wb + (size_t)kt * BK * DD;
      v4f r[8];
      #pragma unroll
      for (int j = 0; j < 8; ++j) r[j] = *(const v4f*)(p + (size_t)j * DD);
      #pragma unroll
      for (int c = 0; c < 4; ++c) {
        v8s h;
        #pragma unroll
        for (int j = 0; j < 8; ++j) h[j] = f2bf(r[j][c]);
        *(v8s*)((char*)sB + SWZ(b_f4 + c, b_k8 * 2)) = h;
      }
    }
    __syncthreads();
    #pragma unroll
    for (int ks = 0; ks < 2; ++ks) {
      const int kb = ks * 64 + lg * 16;
      v8s a[4], b[4];
      #pragma unroll
      for (int m = 0; m < 4; ++m)
        a[m] = *(const v8s*)((const char*)sA + SWZ(wm + m * 16 + lr, kb));
      #pragma unroll
      for (int n = 0; n < 4; ++n)
        b[n] = *(const v8s*)((const char*)sB + SWZ(wn + n * 16 + lr, kb));
      #pragma unroll
      for (int m = 0; m < 4; ++m)
        #pragma unroll
        for (int n = 0; n < 4; ++n)
          acc[m][n] = __builtin_amdgcn_mfma_f32_16x16x32_bf16(a[m], b[n], acc[m][n], 0, 0, 0);
    }
    __syncthreads();
  }
  #pragma unroll
  for (int m = 0; m < 4; ++m)
    #pragma unroll
    for (int r = 0; r < 4; ++r) {
      int row = m0 + wm + m * 16 + lg * 4 + r;
      float wgt = wts[row];
      float* orow = out + (size_t)ids[row] * DD + n0 + wn + lr;
      #pragma unroll
      for (int n = 0; n < 4; ++n)
        atomicAdd(orow + n * 16, wgt * acc[m][n][r]);
    }
}

extern "C" void kernel_launch(void* const* d_in, const int* in_sizes, int n_in,
                              void* d_out, int out_size, void* d_ws, size_t ws_size,
                              hipStream_t stream) {
  const float* x  = (const float*)d_in[0];
  const float* gw = (const float*)d_in[1];
  const float* w1 = (const float*)d_in[2];
  const float* w3 = (const float*)d_in[3];
  const float* w2 = (const float*)d_in[4];
  float* out = (float*)d_out;
  char* ws = (char*)d_ws;

  int*   counts = (int*)(ws + WS_COUNTS);
  int*   fill   = (int*)(ws + WS_FILL);
  int*   rowoff = (int*)(ws + WS_ROWOFF);
  int*   tope   = (int*)(ws + WS_TOPE);
  float* topw   = (float*)(ws + WS_TOPW);
  int*   ids    = (int*)(ws + WS_IDS);
  float* wts    = (float*)(ws + WS_WTS);
  unsigned short* H = (unsigned short*)(ws + WS_H);

  hipMemsetAsync(ws, 0, WS_ZERO, stream);
  hipMemsetAsync(d_out, 0, (size_t)out_size * sizeof(float), stream);

  router_k<<<T_TOK / 4, 256, 0, stream>>>(x, gw, counts, tope, topw);
  offsets_k<<<1, 64, 0, stream>>>(counts, rowoff);
  scatter_k<<<T_TOK / 256, 256, 0, stream>>>(tope, topw, rowoff, fill, ids, wts);
  gemm1_k<<<dim3(FF / BN, MT_MAX), 256, 0, stream>>>(x, w1, w3, counts, rowoff, ids, H);
  gemm2_k<<<dim3(DD / BN, MT_MAX), 256, 0, stream>>>(H, w2, counts, rowoff, ids, wts, out);
}